// Round 1
// 114.655 us; speedup vs baseline: 1.0453x; 1.0453x over previous
//
#include <hip/hip_runtime.h>

// FlowAlignedSmoothingEffect — round 5: interior/border specialization.
//
// R4 post-mortem: VALU-issue-bound (VALUBusy 62%, MfmaUtil 0, HBM 27%).
// ~25 of ~85 VALU/direction-iter are clamp/addressing/inb/accs overhead that
// only matters on image-border tiles (6% of blocks). This round:
//  * 25x25 window (halo 4/5) — taps provably in [-3,+4] px (+1 slot eps slack);
//    27% less staging volume, 10000B LDS, row stride 100 words == 4 mod 32
//    keeps per-row bank rotation.
//  * interior fast path: no clamps (window replication == clamp semantics),
//    no inb (positions can't leave [0,1) when ix in [16,1007]), accs is the
//    block-uniform 2*sum(k), ONE LDS address + immediate offsets +16/+400/+416.
//  * border path: exact old clamp-then-+1 logic (ref clamps x0 BEFORE +1, so
//    the left-border x1 tap must come from clamp(x0)+1, not clamp(x0+1)).
//  * Gaussian k[it] and live-iteration count hoisted (per-batch uniform).
//  * tangent coherence flip via sign-bit XOR (no cmp/cndmask).
//  * XCD-chunked block swizzle (8192 wgs % 8 == 0, bijective) for halo L2 hits.

#define HH 1024
#define WW 1024
#define CC 3
#define BB 2
#define NPIX (HH * WW)

#define TSX 16
#define TSY 16
#define HALO_LO 4
#define NWIN 25            // 4 + 16 + 5

__device__ __forceinline__ unsigned bf16rn(float f) {
    unsigned u = __float_as_uint(f);
    return (u + 0x7fffu + ((u >> 16) & 1u)) >> 16;
}
__device__ __forceinline__ float bf_lo(unsigned u) { return __uint_as_float(u << 16); }
__device__ __forceinline__ float bf_hi(unsigned u) { return __uint_as_float(u & 0xffff0000u); }
__device__ __forceinline__ float uaf(unsigned u)   { return __uint_as_float(u); }

__global__ __launch_bounds__(256) void flow_smooth_lds(
    const float* __restrict__ x, const float* __restrict__ tng,
    const float* __restrict__ sigma, float* __restrict__ out)
{
    __shared__ uint4 win[NWIN * NWIN];    // 625 * 16B = 10000 B

    // ---- XCD-chunked bijective block swizzle (8 XCDs, 8192 wgs) ----
    const int id  = (int)blockIdx.x + ((int)blockIdx.y << 6) + ((int)blockIdx.z << 12);
    const int swz = ((id & 7) << 10) + (id >> 3);
    const int bx = swz & 63;
    const int by = (swz >> 6) & 63;
    const int b  = swz >> 12;

    const int tile_x0 = bx * TSX;
    const int tile_y0 = by * TSY;
    const int win_x0 = tile_x0 - HALO_LO;
    const int win_y0 = tile_y0 - HALO_LO;
    const bool border = (bx == 0) | (bx == 63) | (by == 0) | (by == 63);

    const float* __restrict__ xb  = x   + (size_t)b * CC * NPIX;
    const float* __restrict__ tbx = tng + (size_t)b * 2 * NPIX;
    const float* __restrict__ tby = tbx + NPIX;

    // ---- stage 25x25 window into LDS ----
    if (!border) {
        const int gbase = win_y0 * WW + win_x0;
        for (unsigned j = threadIdx.x; j < NWIN * NWIN; j += 256) {
            const int jy = (int)(j / NWIN);
            const int jx = (int)j - jy * NWIN;
            const int g = gbase + (jy << 10) + jx;
            uint4 rec;
            rec.x = __float_as_uint(tbx[g]);
            rec.y = __float_as_uint(tby[g]);
            rec.z = bf16rn(xb[g]) | (bf16rn(xb[NPIX + g]) << 16);
            rec.w = bf16rn(xb[2 * NPIX + g]);
            win[j] = rec;
        }
    } else {
        for (unsigned j = threadIdx.x; j < NWIN * NWIN; j += 256) {
            const int jy = (int)(j / NWIN);
            const int jx = (int)j - jy * NWIN;
            const int gy = min(max(win_y0 + jy, 0), HH - 1);
            const int gx = min(max(win_x0 + jx, 0), WW - 1);
            const int g = gy * WW + gx;
            uint4 rec;
            rec.x = __float_as_uint(tbx[g]);
            rec.y = __float_as_uint(tby[g]);
            rec.z = bf16rn(xb[g]) | (bf16rn(xb[NPIX + g]) << 16);
            rec.w = bf16rn(xb[2 * NPIX + g]);
            win[j] = rec;
        }
    }
    __syncthreads();

    // ---- per-pixel setup ----
    const int tx = threadIdx.x & (TSX - 1);
    const int ty = threadIdx.x >> 4;
    const int ix = tile_x0 + tx;
    const int iy = tile_y0 + ty;
    const int pix = iy * WW + ix;

    const float sig = sigma[b];
    const float half_width = 2.0f * sig;
    const float inv2s2 = 1.0f / (2.0f * sig * sig);
    const float step = (float)(1.0 / 0.3333);

    // per-batch-uniform Gaussian weights + live trip count (sigma < 6 => <= 3)
    const float r0 = step;
    const float r1 = r0 + step;
    const float r2 = r1 + step;
    const int nlive = (int)(r0 < half_width) + (int)(r1 < half_width) + (int)(r2 < half_width);
    float kk[3];
    kk[0] = __expf(-r0 * r0 * inv2s2);
    kk[1] = __expf(-r1 * r1 * inv2s2);
    kk[2] = __expf(-r2 * r2 * inv2s2);

    // exact f32 center color (global, coalesced, L2-warm) + exact tangent (LDS)
    const float xc0 = xb[pix];
    const float xc1 = xb[NPIX + pix];
    const float xc2 = xb[2 * NPIX + pix];
    const int cidx = (ty + HALO_LO) * NWIN + (tx + HALO_LO);
    const uint2 qc = *reinterpret_cast<const uint2*>(&win[cidx]);
    const float t0x = uaf(qc.x);
    const float t0y = uaf(qc.y);

    const float invW = 1.0f / WW;
    const float invH = 1.0f / HH;

    float acc0 = 0.f, acc1 = 0.f, acc2 = 0.f, accs = 0.f;

    float vx[2], vy[2], px[2], py[2];
    vx[0] = t0x;  vy[0] = t0y;
    vx[1] = -t0x; vy[1] = -t0y;
    const float p0x = ((float)ix + 0.5f) * invW;
    const float p0y = ((float)iy + 0.5f) * invH;
    px[0] = p0x + vx[0] * invW;  py[0] = p0y + vy[0] * invH;
    px[1] = p0x + vx[1] * invW;  py[1] = p0y + vy[1] * invH;

    if (!border) {
        // ===== interior fast path: no clamps, no inb, uniform accs =====
        const int winoff = win_y0 * NWIN + win_x0;
        #pragma unroll
        for (int it = 0; it < 3; ++it) {
            if (it >= nlive) break;
            const float k = kk[it];
            #pragma unroll
            for (int c = 0; c < 2; ++c) {
                const float fx = fmaf(px[c], (float)WW, -0.5f);
                const float fy = fmaf(py[c], (float)HH, -0.5f);
                const float x0f = floorf(fx);
                const float y0f = floorf(fy);
                const float wx = fx - x0f;
                const float wy = fy - y0f;
                const int idx = (int)y0f * NWIN + (int)x0f - winoff;

                const uint4 q00 = win[idx];
                const uint4 q01 = win[idx + 1];
                const uint4 q10 = win[idx + NWIN];
                const uint4 q11 = win[idx + NWIN + 1];

                const float wxm = 1.f - wx, wym = 1.f - wy;
                const float w00 = wxm * wym, w01 = wx * wym;
                const float w10 = wxm * wy,  w11 = wx * wy;

                float tfx = uaf(q00.x) * w00 + uaf(q01.x) * w01
                          + uaf(q10.x) * w10 + uaf(q11.x) * w11;
                float tfy = uaf(q00.y) * w00 + uaf(q01.y) * w01
                          + uaf(q10.y) * w10 + uaf(q11.y) * w11;

                const float k00 = k * w00, k01 = k * w01;
                const float k10 = k * w10, k11 = k * w11;
                acc0 += bf_lo(q00.z) * k00 + bf_lo(q01.z) * k01
                      + bf_lo(q10.z) * k10 + bf_lo(q11.z) * k11;
                acc1 += bf_hi(q00.z) * k00 + bf_hi(q01.z) * k01
                      + bf_hi(q10.z) * k10 + bf_hi(q11.z) * k11;
                acc2 += bf_lo(q00.w) * k00 + bf_lo(q01.w) * k01
                      + bf_lo(q10.w) * k10 + bf_lo(q11.w) * k11;

                // direction coherence: flip sign iff vt < 0 (sign-bit xor)
                const float vt = vx[c] * tfx + vy[c] * tfy;
                const unsigned sgn = __float_as_uint(vt) & 0x80000000u;
                tfx = __uint_as_float(__float_as_uint(tfx) ^ sgn);
                tfy = __uint_as_float(__float_as_uint(tfy) ^ sgn);
                vx[c] = tfx; vy[c] = tfy;
                px[c] += tfx * invW;
                py[c] += tfy * invH;
            }
        }
        // accs is block-uniform in the interior (inb always true)
        float ks = 0.f;
        if (nlive > 0) ks += kk[0];
        if (nlive > 1) ks += kk[1];
        if (nlive > 2) ks += kk[2];
        accs = 2.0f * ks;
    } else {
        // ===== border path: exact reference clamp semantics =====
        #pragma unroll
        for (int it = 0; it < 3; ++it) {
            if (it >= nlive) break;
            const float k = kk[it];
            #pragma unroll
            for (int c = 0; c < 2; ++c) {
                const float fx = fmaf(px[c], (float)WW, -0.5f);
                const float fy = fmaf(py[c], (float)HH, -0.5f);
                const float x0f = floorf(fx);
                const float y0f = floorf(fy);
                const float wx = fx - x0f;      // weights from UNclamped floor
                const float wy = fy - y0f;
                int x0i = (int)x0f;
                int y0i = (int)y0f;
                x0i = min(max(x0i, 0), WW - 1); // clamp BEFORE +1 (ref order)
                y0i = min(max(y0i, 0), HH - 1);
                const int x1i = min(x0i + 1, WW - 1);
                const int y1i = min(y0i + 1, HH - 1);

                const int jx0 = x0i - win_x0;
                const int jx1 = x1i - win_x0;
                const int jy0 = y0i - win_y0;
                const int jy1 = y1i - win_y0;

                const uint4 q00 = win[jy0 * NWIN + jx0];
                const uint4 q01 = win[jy0 * NWIN + jx1];
                const uint4 q10 = win[jy1 * NWIN + jx0];
                const uint4 q11 = win[jy1 * NWIN + jx1];

                const float wxm = 1.f - wx, wym = 1.f - wy;
                const float w00 = wxm * wym, w01 = wx * wym;
                const float w10 = wxm * wy,  w11 = wx * wy;

                float tfx = uaf(q00.x) * w00 + uaf(q01.x) * w01
                          + uaf(q10.x) * w10 + uaf(q11.x) * w11;
                float tfy = uaf(q00.y) * w00 + uaf(q01.y) * w01
                          + uaf(q10.y) * w10 + uaf(q11.y) * w11;

                const bool inb = (px[c] >= 0.f) & (px[c] < 1.f) &
                                 (py[c] >= 0.f) & (py[c] < 1.f);
                const float kg = inb ? k : 0.f;
                const float k00 = kg * w00, k01 = kg * w01;
                const float k10 = kg * w10, k11 = kg * w11;
                acc0 += bf_lo(q00.z) * k00 + bf_lo(q01.z) * k01
                      + bf_lo(q10.z) * k10 + bf_lo(q11.z) * k11;
                acc1 += bf_hi(q00.z) * k00 + bf_hi(q01.z) * k01
                      + bf_hi(q10.z) * k10 + bf_hi(q11.z) * k11;
                acc2 += bf_lo(q00.w) * k00 + bf_lo(q01.w) * k01
                      + bf_lo(q10.w) * k10 + bf_lo(q11.w) * k11;
                accs += kg;

                const float vt = vx[c] * tfx + vy[c] * tfy;
                const unsigned sgn = __float_as_uint(vt) & 0x80000000u;
                tfx = __uint_as_float(__float_as_uint(tfx) ^ sgn);
                tfy = __uint_as_float(__float_as_uint(tfy) ^ sgn);
                vx[c] = tfx; vy[c] = tfy;
                px[c] += tfx * invW;
                py[c] += tfy * invH;
            }
        }
    }

    const float inv_den = 1.0f / (1.0f + accs);
    float* ob = out + (size_t)b * CC * NPIX;
    ob[pix]            = (xc0 + acc0) * inv_den;
    ob[NPIX + pix]     = (xc1 + acc1) * inv_den;
    ob[2 * NPIX + pix] = (xc2 + acc2) * inv_den;
}

extern "C" void kernel_launch(void* const* d_in, const int* in_sizes, int n_in,
                              void* d_out, int out_size, void* d_ws, size_t ws_size,
                              hipStream_t stream) {
    const float* x  = (const float*)d_in[0];
    const float* t  = (const float*)d_in[1];
    const float* sg = (const float*)d_in[2];
    float* out = (float*)d_out;

    dim3 grid(WW / TSX, HH / TSY, BB);
    flow_smooth_lds<<<grid, dim3(256), 0, stream>>>(x, t, sg, out);
}

// Round 2
// 108.400 us; speedup vs baseline: 1.1056x; 1.0577x over previous
//
#include <hip/hip_runtime.h>
#include <hip/hip_fp16.h>

// FlowAlignedSmoothingEffect — round 6: split 8B LDS records + packed-f16 color.
//
// R5 post-mortem: VALU-issue + LDS-conflict bound (VALUBusy 57%, HBM 13%,
// SQ_LDS_BANK_CONFLICT 12.4M ~= 45% of kernel cycles). The 16B uint4 record
// leaves only 8 bank-groups -> 8-way conflicts on every ds_read_b128.
// This round:
//  * split window into tanw (float2, EXACT f32 — march path untouched) and
//    colw (uint2 = {(c0,c1) f16x2, (c2,0) f16x2}): 8B granule -> 16 bank-pair
//    columns -> 4 lanes/column = b64 structural minimum (conflicts ~free);
//    adjacent idx/idx+1 reads fuse into ds_read2_b64.
//  * color bilinear in packed f16 (__hfma2), accumulate in f32: 18 ops/tap
//    vs 28 scalar-bf16. f16 storage (2^-11) beats bf16 (2^-8) -> absmax drops.
//  * last live iteration skips tangent interp/flip/update (dead values):
//    -15 VALU and -2 LDS reads per direction.
//  * march arithmetic (fmaf(px,1024,-0.5), 4-term tf sum, sign-xor flip) is
//    BIT-IDENTICAL to R5 — vt sign path is divergence-sensitive, don't touch.
//  * geometry unchanged: 25x25 window, halo 4/5, XCD-chunked swizzle.

#define HH 1024
#define WW 1024
#define CC 3
#define BB 2
#define NPIX (HH * WW)

#define TSX 16
#define TSY 16
#define HALO_LO 4
#define NWIN 25            // 4 + 16 + 5

__device__ __forceinline__ float uaf(unsigned u) { return __uint_as_float(u); }
__device__ __forceinline__ __half2 h2(unsigned u) {
    __half2 r; *(unsigned*)&r = u; return r;
}

__global__ __launch_bounds__(256) void flow_smooth_lds(
    const float* __restrict__ x, const float* __restrict__ tng,
    const float* __restrict__ sigma, float* __restrict__ out)
{
    __shared__ float2 tanw[NWIN * NWIN];   // 5000 B, f32 tangent (exact)
    __shared__ uint2  colw[NWIN * NWIN];   // 5000 B, colors packed f16

    // ---- XCD-chunked bijective block swizzle (8 XCDs, 8192 wgs) ----
    const int id  = (int)blockIdx.x + ((int)blockIdx.y << 6) + ((int)blockIdx.z << 12);
    const int swz = ((id & 7) << 10) + (id >> 3);
    const int bx = swz & 63;
    const int by = (swz >> 6) & 63;
    const int b  = swz >> 12;

    const int tile_x0 = bx * TSX;
    const int tile_y0 = by * TSY;
    const int win_x0 = tile_x0 - HALO_LO;
    const int win_y0 = tile_y0 - HALO_LO;
    const bool border = (bx == 0) | (bx == 63) | (by == 0) | (by == 63);

    const float* __restrict__ xb  = x   + (size_t)b * CC * NPIX;
    const float* __restrict__ tbx = tng + (size_t)b * 2 * NPIX;
    const float* __restrict__ tby = tbx + NPIX;

    // ---- stage 25x25 window into LDS ----
    if (!border) {
        const int gbase = win_y0 * WW + win_x0;
        for (unsigned j = threadIdx.x; j < NWIN * NWIN; j += 256) {
            const int jy = (int)(j / NWIN);
            const int jx = (int)j - jy * NWIN;
            const int g = gbase + (jy << 10) + jx;
            tanw[j] = make_float2(tbx[g], tby[g]);
            const __half2 c01 = __floats2half2_rn(xb[g], xb[NPIX + g]);
            const __half2 c2p = __floats2half2_rn(xb[2 * NPIX + g], 0.f);
            uint2 r;
            r.x = *(const unsigned*)&c01;
            r.y = *(const unsigned*)&c2p;
            colw[j] = r;
        }
    } else {
        for (unsigned j = threadIdx.x; j < NWIN * NWIN; j += 256) {
            const int jy = (int)(j / NWIN);
            const int jx = (int)j - jy * NWIN;
            const int gy = min(max(win_y0 + jy, 0), HH - 1);
            const int gx = min(max(win_x0 + jx, 0), WW - 1);
            const int g = gy * WW + gx;
            tanw[j] = make_float2(tbx[g], tby[g]);
            const __half2 c01 = __floats2half2_rn(xb[g], xb[NPIX + g]);
            const __half2 c2p = __floats2half2_rn(xb[2 * NPIX + g], 0.f);
            uint2 r;
            r.x = *(const unsigned*)&c01;
            r.y = *(const unsigned*)&c2p;
            colw[j] = r;
        }
    }
    __syncthreads();

    // ---- per-pixel setup ----
    const int tx = threadIdx.x & (TSX - 1);
    const int ty = threadIdx.x >> 4;
    const int ix = tile_x0 + tx;
    const int iy = tile_y0 + ty;
    const int pix = iy * WW + ix;

    const float sig = sigma[b];
    const float half_width = 2.0f * sig;
    const float inv2s2 = 1.0f / (2.0f * sig * sig);
    const float step = (float)(1.0 / 0.3333);

    // per-batch-uniform Gaussian weights + live trip count (sigma < 6 => <= 3)
    const float r0 = step;
    const float r1 = r0 + step;
    const float r2 = r1 + step;
    const int nlive = (int)(r0 < half_width) + (int)(r1 < half_width) + (int)(r2 < half_width);
    const float kk0 = __expf(-r0 * r0 * inv2s2);
    const float kk1 = __expf(-r1 * r1 * inv2s2);
    const float kk2 = __expf(-r2 * r2 * inv2s2);

    // exact f32 center color (global, coalesced, L2-warm) + exact tangent (LDS)
    const float xc0 = xb[pix];
    const float xc1 = xb[NPIX + pix];
    const float xc2 = xb[2 * NPIX + pix];
    const int cidx = (ty + HALO_LO) * NWIN + (tx + HALO_LO);
    const float2 tc = tanw[cidx];
    const float t0x = tc.x;
    const float t0y = tc.y;

    const float invW = 1.0f / WW;
    const float invH = 1.0f / HH;

    float acc0 = 0.f, acc1 = 0.f, acc2 = 0.f, accs = 0.f;

    float vx[2], vy[2], px[2], py[2];
    vx[0] = t0x;  vy[0] = t0y;
    vx[1] = -t0x; vy[1] = -t0y;
    const float p0x = ((float)ix + 0.5f) * invW;
    const float p0y = ((float)iy + 0.5f) * invH;
    px[0] = p0x + vx[0] * invW;  py[0] = p0y + vy[0] * invH;
    px[1] = p0x + vx[1] * invW;  py[1] = p0y + vy[1] * invH;

    if (!border) {
        // ===== interior fast path =====
        const int winoff = win_y0 * NWIN + win_x0;
        #pragma unroll
        for (int it = 0; it < 3; ++it) {
            if (it >= nlive) break;
            const float k = (it == 0) ? kk0 : (it == 1) ? kk1 : kk2;
            const bool need_t = (it + 1 < nlive);   // last live iter: march is dead
            #pragma unroll
            for (int c = 0; c < 2; ++c) {
                const float fx = fmaf(px[c], (float)WW, -0.5f);
                const float fy = fmaf(py[c], (float)HH, -0.5f);
                const float x0f = floorf(fx);
                const float y0f = floorf(fy);
                const float wx = fx - x0f;
                const float wy = fy - y0f;
                const int idx = (int)y0f * NWIN + (int)x0f - winoff;

                const float wxm = 1.f - wx, wym = 1.f - wy;
                const float w00 = wxm * wym, w01 = wx * wym;
                const float w10 = wxm * wy,  w11 = wx * wy;

                // packed-f16 color bilinear (accumulate in f32)
                const uint2 q00 = colw[idx];
                const uint2 q01 = colw[idx + 1];
                const uint2 q10 = colw[idx + NWIN];
                const uint2 q11 = colw[idx + NWIN + 1];
                const __half2 h00 = __float2half2_rn(w00);
                const __half2 h01 = __float2half2_rn(w01);
                const __half2 h10 = __float2half2_rn(w10);
                const __half2 h11 = __float2half2_rn(w11);
                __half2 a01 = __hmul2(h00, h2(q00.x));
                a01 = __hfma2(h01, h2(q01.x), a01);
                a01 = __hfma2(h10, h2(q10.x), a01);
                a01 = __hfma2(h11, h2(q11.x), a01);
                __half2 a2 = __hmul2(h00, h2(q00.y));
                a2 = __hfma2(h01, h2(q01.y), a2);
                a2 = __hfma2(h10, h2(q10.y), a2);
                a2 = __hfma2(h11, h2(q11.y), a2);
                acc0 = fmaf(k, __low2float(a01), acc0);
                acc1 = fmaf(k, __high2float(a01), acc1);
                acc2 = fmaf(k, __low2float(a2), acc2);

                if (need_t) {
                    // exact-f32 tangent interp + coherence flip (R5-identical)
                    const float2 t00 = tanw[idx];
                    const float2 t01 = tanw[idx + 1];
                    const float2 t10 = tanw[idx + NWIN];
                    const float2 t11 = tanw[idx + NWIN + 1];
                    float tfx = t00.x * w00 + t01.x * w01 + t10.x * w10 + t11.x * w11;
                    float tfy = t00.y * w00 + t01.y * w01 + t10.y * w10 + t11.y * w11;
                    const float vt = vx[c] * tfx + vy[c] * tfy;
                    const unsigned sgn = __float_as_uint(vt) & 0x80000000u;
                    tfx = __uint_as_float(__float_as_uint(tfx) ^ sgn);
                    tfy = __uint_as_float(__float_as_uint(tfy) ^ sgn);
                    vx[c] = tfx; vy[c] = tfy;
                    px[c] += tfx * invW;
                    py[c] += tfy * invH;
                }
            }
        }
        // accs is block-uniform in the interior (inb always true)
        float ks = 0.f;
        if (nlive > 0) ks += kk0;
        if (nlive > 1) ks += kk1;
        if (nlive > 2) ks += kk2;
        accs = 2.0f * ks;
    } else {
        // ===== border path: exact reference clamp semantics =====
        #pragma unroll
        for (int it = 0; it < 3; ++it) {
            if (it >= nlive) break;
            const float k = (it == 0) ? kk0 : (it == 1) ? kk1 : kk2;
            #pragma unroll
            for (int c = 0; c < 2; ++c) {
                const float fx = fmaf(px[c], (float)WW, -0.5f);
                const float fy = fmaf(py[c], (float)HH, -0.5f);
                const float x0f = floorf(fx);
                const float y0f = floorf(fy);
                const float wx = fx - x0f;      // weights from UNclamped floor
                const float wy = fy - y0f;
                int x0i = (int)x0f;
                int y0i = (int)y0f;
                x0i = min(max(x0i, 0), WW - 1); // clamp BEFORE +1 (ref order)
                y0i = min(max(y0i, 0), HH - 1);
                const int x1i = min(x0i + 1, WW - 1);
                const int y1i = min(y0i + 1, HH - 1);

                const int jx0 = x0i - win_x0;
                const int jx1 = x1i - win_x0;
                const int jy0 = y0i - win_y0;
                const int jy1 = y1i - win_y0;
                const int i00 = jy0 * NWIN + jx0;
                const int i01 = jy0 * NWIN + jx1;
                const int i10 = jy1 * NWIN + jx0;
                const int i11 = jy1 * NWIN + jx1;

                const float wxm = 1.f - wx, wym = 1.f - wy;
                const float w00 = wxm * wym, w01 = wx * wym;
                const float w10 = wxm * wy,  w11 = wx * wy;

                const bool inb = (px[c] >= 0.f) & (px[c] < 1.f) &
                                 (py[c] >= 0.f) & (py[c] < 1.f);
                const float kg = inb ? k : 0.f;

                const uint2 q00 = colw[i00];
                const uint2 q01 = colw[i01];
                const uint2 q10 = colw[i10];
                const uint2 q11 = colw[i11];
                const __half2 h00 = __float2half2_rn(w00);
                const __half2 h01 = __float2half2_rn(w01);
                const __half2 h10 = __float2half2_rn(w10);
                const __half2 h11 = __float2half2_rn(w11);
                __half2 a01 = __hmul2(h00, h2(q00.x));
                a01 = __hfma2(h01, h2(q01.x), a01);
                a01 = __hfma2(h10, h2(q10.x), a01);
                a01 = __hfma2(h11, h2(q11.x), a01);
                __half2 a2 = __hmul2(h00, h2(q00.y));
                a2 = __hfma2(h01, h2(q01.y), a2);
                a2 = __hfma2(h10, h2(q10.y), a2);
                a2 = __hfma2(h11, h2(q11.y), a2);
                acc0 = fmaf(kg, __low2float(a01), acc0);
                acc1 = fmaf(kg, __high2float(a01), acc1);
                acc2 = fmaf(kg, __low2float(a2), acc2);
                accs += kg;

                const float2 t00 = tanw[i00];
                const float2 t01 = tanw[i01];
                const float2 t10 = tanw[i10];
                const float2 t11 = tanw[i11];
                float tfx = t00.x * w00 + t01.x * w01 + t10.x * w10 + t11.x * w11;
                float tfy = t00.y * w00 + t01.y * w01 + t10.y * w10 + t11.y * w11;
                const float vt = vx[c] * tfx + vy[c] * tfy;
                const unsigned sgn = __float_as_uint(vt) & 0x80000000u;
                tfx = __uint_as_float(__float_as_uint(tfx) ^ sgn);
                tfy = __uint_as_float(__float_as_uint(tfy) ^ sgn);
                vx[c] = tfx; vy[c] = tfy;
                px[c] += tfx * invW;
                py[c] += tfy * invH;
            }
        }
    }

    const float inv_den = 1.0f / (1.0f + accs);
    float* ob = out + (size_t)b * CC * NPIX;
    ob[pix]            = (xc0 + acc0) * inv_den;
    ob[NPIX + pix]     = (xc1 + acc1) * inv_den;
    ob[2 * NPIX + pix] = (xc2 + acc2) * inv_den;
}

extern "C" void kernel_launch(void* const* d_in, const int* in_sizes, int n_in,
                              void* d_out, int out_size, void* d_ws, size_t ws_size,
                              hipStream_t stream) {
    const float* x  = (const float*)d_in[0];
    const float* t  = (const float*)d_in[1];
    const float* sg = (const float*)d_in[2];
    float* out = (float*)d_out;

    dim3 grid(WW / TSX, HH / TSY, BB);
    flow_smooth_lds<<<grid, dim3(256), 0, stream>>>(x, t, sg, out);
}